// Round 1
// baseline (243.023 us; speedup 1.0000x reference)
//
#include <hip/hip_runtime.h>

// IF neuron, multi-step, hard reset:
//   h_t = x_t + v_{t-1};  s_t = (h_t - 1.0 >= 0);  v_t = s_t ? 0 : h_t
// Independent per (b,d) element -> one thread per 4 elements (float4),
// sequential loop over T. Purely HBM-bound (~260 MiB traffic).

template <int T>
__global__ __launch_bounds__(256) void if_node_vec4_fixed(
    const float* __restrict__ x,    // (T, N) flattened
    const float* __restrict__ v0,   // (N,)
    float* __restrict__ out,        // (T, N)
    long n4)                        // N/4
{
    long i = (long)blockIdx.x * blockDim.x + threadIdx.x;
    if (i >= n4) return;

    const float4* x4  = (const float4*)x;
    const float4* v04 = (const float4*)v0;
    float4*       o4  = (float4*)out;

    float4 v = v04[i];

#pragma unroll
    for (int t = 0; t < T; ++t) {
        float4 xv = x4[(long)t * n4 + i];
        float hx = xv.x + v.x;
        float hy = xv.y + v.y;
        float hz = xv.z + v.z;
        float hw = xv.w + v.w;
        bool sx = (hx - 1.0f) >= 0.0f;
        bool sy = (hy - 1.0f) >= 0.0f;
        bool sz = (hz - 1.0f) >= 0.0f;
        bool sw = (hw - 1.0f) >= 0.0f;
        float4 s;
        s.x = sx ? 1.0f : 0.0f;
        s.y = sy ? 1.0f : 0.0f;
        s.z = sz ? 1.0f : 0.0f;
        s.w = sw ? 1.0f : 0.0f;
        v.x = sx ? 0.0f : hx;
        v.y = sy ? 0.0f : hy;
        v.z = sz ? 0.0f : hz;
        v.w = sw ? 0.0f : hw;
        o4[(long)t * n4 + i] = s;
    }
}

// Generic fallbacks (runtime T, or N not divisible by 4).
__global__ __launch_bounds__(256) void if_node_vec4_generic(
    const float* __restrict__ x, const float* __restrict__ v0,
    float* __restrict__ out, long n4, int T)
{
    long i = (long)blockIdx.x * blockDim.x + threadIdx.x;
    if (i >= n4) return;
    const float4* x4  = (const float4*)x;
    const float4* v04 = (const float4*)v0;
    float4*       o4  = (float4*)out;
    float4 v = v04[i];
    for (int t = 0; t < T; ++t) {
        float4 xv = x4[(long)t * n4 + i];
        float hx = xv.x + v.x;
        float hy = xv.y + v.y;
        float hz = xv.z + v.z;
        float hw = xv.w + v.w;
        bool sx = (hx - 1.0f) >= 0.0f;
        bool sy = (hy - 1.0f) >= 0.0f;
        bool sz = (hz - 1.0f) >= 0.0f;
        bool sw = (hw - 1.0f) >= 0.0f;
        float4 s;
        s.x = sx ? 1.0f : 0.0f;
        s.y = sy ? 1.0f : 0.0f;
        s.z = sz ? 1.0f : 0.0f;
        s.w = sw ? 1.0f : 0.0f;
        v.x = sx ? 0.0f : hx;
        v.y = sy ? 0.0f : hy;
        v.z = sz ? 0.0f : hz;
        v.w = sw ? 0.0f : hw;
        o4[(long)t * n4 + i] = s;
    }
}

__global__ __launch_bounds__(256) void if_node_scalar(
    const float* __restrict__ x, const float* __restrict__ v0,
    float* __restrict__ out, long n, int T)
{
    long i = (long)blockIdx.x * blockDim.x + threadIdx.x;
    if (i >= n) return;
    float v = v0[i];
    for (int t = 0; t < T; ++t) {
        float h = x[(long)t * n + i] + v;
        bool s = (h - 1.0f) >= 0.0f;
        out[(long)t * n + i] = s ? 1.0f : 0.0f;
        v = s ? 0.0f : h;
    }
}

extern "C" void kernel_launch(void* const* d_in, const int* in_sizes, int n_in,
                              void* d_out, int out_size, void* d_ws, size_t ws_size,
                              hipStream_t stream) {
    const float* x  = (const float*)d_in[0];   // (T, B, D) fp32
    const float* v0 = (const float*)d_in[1];   // (B, D) fp32
    float* out = (float*)d_out;                // (T, B, D) fp32

    long n = in_sizes[1];                      // B*D
    int  T = (int)(in_sizes[0] / n);           // 32

    if ((n & 3) == 0) {
        long n4 = n >> 2;
        int block = 256;
        long grid = (n4 + block - 1) / block;
        if (T == 32) {
            if_node_vec4_fixed<32><<<dim3((unsigned)grid), dim3(block), 0, stream>>>(
                x, v0, out, n4);
        } else {
            if_node_vec4_generic<<<dim3((unsigned)grid), dim3(block), 0, stream>>>(
                x, v0, out, n4, T);
        }
    } else {
        int block = 256;
        long grid = (n + block - 1) / block;
        if_node_scalar<<<dim3((unsigned)grid), dim3(block), 0, stream>>>(
            x, v0, out, n, T);
    }
}

// Round 3
// 237.614 us; speedup vs baseline: 1.0228x; 1.0228x over previous
//
#include <hip/hip_runtime.h>

// IF neuron, multi-step, hard reset:
//   h_t = x_t + v_{t-1};  s_t = (h_t - 1.0 >= 0);  v_t = s_t ? 0 : h_t
//
// R2: same plan as R1 (float2 granularity -> 32 waves/CU; 8-deep register
// prefetch pipeline; non-temporal stores), but using clang native
// ext_vector_type instead of HIP_vector_type so
// __builtin_nontemporal_store accepts it.

typedef float v2f __attribute__((ext_vector_type(2)));

template <int T, int KB>
__global__ __launch_bounds__(256) void if_node_f2_pipe(
    const float* __restrict__ x,    // (T, N)
    const float* __restrict__ v0,   // (N,)
    float* __restrict__ out,        // (T, N)
    long n2)                        // N/2
{
    long i = (long)blockIdx.x * blockDim.x + threadIdx.x;
    if (i >= n2) return;

    const v2f* __restrict__ x2 = (const v2f*)x;
    v2f*       __restrict__ o2 = (v2f*)out;

    v2f v = ((const v2f*)v0)[i];

    constexpr int G = T / KB;  // groups
    v2f cur[KB];
    v2f nxt[KB];

#pragma unroll
    for (int k = 0; k < KB; ++k)
        cur[k] = x2[(long)k * n2 + i];

#pragma unroll
    for (int g = 0; g < G; ++g) {
        // Issue next group's loads before consuming current group.
        if (g + 1 < G) {
#pragma unroll
            for (int k = 0; k < KB; ++k)
                nxt[k] = x2[(long)((g + 1) * KB + k) * n2 + i];
        }
#pragma unroll
        for (int k = 0; k < KB; ++k) {
            float hx = cur[k].x + v.x;
            float hy = cur[k].y + v.y;
            bool sx = (hx - 1.0f) >= 0.0f;
            bool sy = (hy - 1.0f) >= 0.0f;
            v2f s;
            s.x = sx ? 1.0f : 0.0f;
            s.y = sy ? 1.0f : 0.0f;
            v.x = sx ? 0.0f : hx;
            v.y = sy ? 0.0f : hy;
            __builtin_nontemporal_store(s, &o2[(long)(g * KB + k) * n2 + i]);
        }
        if (g + 1 < G) {
#pragma unroll
            for (int k = 0; k < KB; ++k)
                cur[k] = nxt[k];
        }
    }
}

// Fallbacks for shapes the fast path doesn't cover.
__global__ __launch_bounds__(256) void if_node_f2_generic(
    const float* __restrict__ x, const float* __restrict__ v0,
    float* __restrict__ out, long n2, int T)
{
    long i = (long)blockIdx.x * blockDim.x + threadIdx.x;
    if (i >= n2) return;
    const v2f* x2 = (const v2f*)x;
    v2f*       o2 = (v2f*)out;
    v2f v = ((const v2f*)v0)[i];
    for (int t = 0; t < T; ++t) {
        v2f xv = x2[(long)t * n2 + i];
        float hx = xv.x + v.x;
        float hy = xv.y + v.y;
        bool sx = (hx - 1.0f) >= 0.0f;
        bool sy = (hy - 1.0f) >= 0.0f;
        v2f s;
        s.x = sx ? 1.0f : 0.0f;
        s.y = sy ? 1.0f : 0.0f;
        v.x = sx ? 0.0f : hx;
        v.y = sy ? 0.0f : hy;
        o2[(long)t * n2 + i] = s;
    }
}

__global__ __launch_bounds__(256) void if_node_scalar(
    const float* __restrict__ x, const float* __restrict__ v0,
    float* __restrict__ out, long n, int T)
{
    long i = (long)blockIdx.x * blockDim.x + threadIdx.x;
    if (i >= n) return;
    float v = v0[i];
    for (int t = 0; t < T; ++t) {
        float h = x[(long)t * n + i] + v;
        bool s = (h - 1.0f) >= 0.0f;
        out[(long)t * n + i] = s ? 1.0f : 0.0f;
        v = s ? 0.0f : h;
    }
}

extern "C" void kernel_launch(void* const* d_in, const int* in_sizes, int n_in,
                              void* d_out, int out_size, void* d_ws, size_t ws_size,
                              hipStream_t stream) {
    const float* x  = (const float*)d_in[0];   // (T, B, D) fp32
    const float* v0 = (const float*)d_in[1];   // (B, D) fp32
    float* out = (float*)d_out;                // (T, B, D) fp32

    long n = in_sizes[1];                      // B*D
    int  T = (int)(in_sizes[0] / n);           // 32

    int block = 256;
    if (T == 32 && (n & 1) == 0) {
        long n2 = n >> 1;
        long grid = (n2 + block - 1) / block;
        if_node_f2_pipe<32, 8><<<dim3((unsigned)grid), dim3(block), 0, stream>>>(
            x, v0, out, n2);
    } else if ((n & 1) == 0) {
        long n2 = n >> 1;
        long grid = (n2 + block - 1) / block;
        if_node_f2_generic<<<dim3((unsigned)grid), dim3(block), 0, stream>>>(
            x, v0, out, n2, T);
    } else {
        long grid = (n + block - 1) / block;
        if_node_scalar<<<dim3((unsigned)grid), dim3(block), 0, stream>>>(
            x, v0, out, n, T);
    }
}